// Round 1
// 289.149 us; speedup vs baseline: 1.0149x; 1.0149x over previous
//
#include <hip/hip_runtime.h>

// Problem constants (fixed by setup_inputs)
#define Bb 32
#define Cc 4
#define Hh 512
#define Ww 512
#define Tt 64
#define HW (Hh * Ww)            // 262144
#define NTOT ((long long)Bb * Cc * Hh * Ww)  // 33,554,432
#define NQUAD (Bb * HW / 4)     // 2,097,152 quads (4 pixels x 4 channels each)

// Main-kernel grid: 2048 blocks x 256 threads, grid-stride, 4 quads/thread.
#define GRID2 2048
#define ITER2 (NQUAD / (GRID2 * 256))   // = 4 exactly

// ws layout:
//   [0 .. GRID2*8)                  : double partials[GRID2]   (16 KiB)
//   [65536 .. 65536 + B*H*8*8)      : uint64 rowmask[B*H][8]   (1 MiB)
#define ROWMASK_OFF 65536

// ---------------------------------------------------------------------------
// Kernel 1: build per-(b,h) column bitmask (512 bits = 8 u64 words per row).
// One thread per image row. Every word is written, so no zero-init of ws needed.
// ---------------------------------------------------------------------------
__global__ __launch_bounds__(256) void build_rowmask_kernel(
    const float* __restrict__ pos,                // [B, T, 2] (x, y)
    unsigned long long* __restrict__ rowmask)     // [B*H][8]
{
    int row = blockIdx.x * 256 + threadIdx.x;     // 0 .. B*H-1
    if (row >= Bb * Hh) return;
    int b = row >> 9;     // row / 512
    int h = row & 511;

    unsigned long long m[8];
#pragma unroll
    for (int i = 0; i < 8; ++i) m[i] = 0ull;

    const float* p = pos + (size_t)b * Tt * 2;
    for (int t = 0; t < Tt; ++t) {
        float x = p[2 * t + 0];
        float y = p[2 * t + 1];
        if (!(x > 0.0f && y > 0.0f)) continue;
        int xp = (int)floorf(x * (float)Ww);
        int yp = (int)floorf(y * (float)Hh);
        if (h < yp - 5 || h >= yp + 5) continue;  // row not covered by this box
        int xlo = xp - 5; if (xlo < 0) xlo = 0;
        int xhi = xp + 5; if (xhi > Ww) xhi = Ww;
        if (xlo >= xhi) continue;
        int w0 = xlo >> 6;
        int w1 = (xhi - 1) >> 6;
        for (int wd = w0; wd <= w1; ++wd) {
            int lo = xlo - (wd << 6); if (lo < 0) lo = 0;
            int hi = xhi - (wd << 6); if (hi > 64) hi = 64;
            // hi - lo <= 10 < 64, shift is safe
            m[wd] |= (((1ull << (hi - lo)) - 1ull) << lo);
        }
    }

    unsigned long long* out = rowmask + (size_t)row * 8;
#pragma unroll
    for (int i = 0; i < 8; ++i) out[i] = m[i];
}

// ---------------------------------------------------------------------------
// Kernel 2: main weighted squared-difference reduction.
// Grid-stride version: 2048 blocks (8 blocks/CU resident), each thread owns
// 4 quads (one quad = 4 consecutive pixels across all 4 channels).
// Keeps a continuous stream of float4 loads in flight per wave instead of
// one burst + retire per tiny block; reduction/barrier cost amortized 4x.
// ---------------------------------------------------------------------------
__global__ __launch_bounds__(256, 8) void weighted_sq_sum_kernel(
    const float* __restrict__ pred,
    const float* __restrict__ targ,
    const unsigned long long* __restrict__ rowmask,
    double* __restrict__ partials)
{
    const int tid0 = blockIdx.x * 256 + threadIdx.x;   // 0 .. 524287
    const int PS = HW / 4;                             // plane stride in float4s

    double acc = 0.0;
#pragma unroll
    for (int it = 0; it < ITER2; ++it) {
        int gid = tid0 + it * (GRID2 * 256);    // quad id, exact cover
        int b   = gid >> 16;                    // / (HW/4 = 65536)
        int rem = gid & 65535;
        int h   = rem >> 7;                     // / (W/4 = 128)
        int w   = (rem & 127) << 2;

        size_t base = (size_t)b * (Cc * HW) + (size_t)h * Ww + (size_t)w;
        const float4* p4 = (const float4*)(pred + base);
        const float4* t4 = (const float4*)(targ + base);

        // mask word for this 64-column granule; 4 bits for this quad
        unsigned long long word = rowmask[((size_t)b * Hh + h) * 8 + (w >> 6)];
        unsigned bits = (unsigned)((word >> (w & 63)) & 0xFull);

        float sx = 0.f, sy = 0.f, sz = 0.f, sw = 0.f;
#pragma unroll
        for (int c = 0; c < Cc; ++c) {
            float4 a = p4[(size_t)c * PS];
            float4 t = t4[(size_t)c * PS];
            float dx = a.x - t.x, dy = a.y - t.y, dz = a.z - t.z, dw = a.w - t.w;
            sx += dx * dx; sy += dy * dy; sz += dz * dz; sw += dw * dw;
        }

        float tot  = sx + sy + sz + sw;
        float msum = (bits & 1u ? sx : 0.f) + (bits & 2u ? sy : 0.f) +
                     (bits & 4u ? sz : 0.f) + (bits & 8u ? sw : 0.f);
        acc += (double)tot + 3.0 * (double)msum;
    }

    // wave (64-lane) reduction
#pragma unroll
    for (int off = 32; off > 0; off >>= 1)
        acc += __shfl_down(acc, off, 64);

    __shared__ double lsum[4];
    int lane = threadIdx.x & 63;
    int wid  = threadIdx.x >> 6;
    if (lane == 0) lsum[wid] = acc;
    __syncthreads();
    if (threadIdx.x == 0)
        partials[blockIdx.x] = lsum[0] + lsum[1] + lsum[2] + lsum[3];
}

// ---------------------------------------------------------------------------
// Kernel 3: reduce 2048 partials, scale by 1/N, write scalar fp32 output.
// ---------------------------------------------------------------------------
__global__ __launch_bounds__(256) void final_reduce_kernel(
    const double* __restrict__ partials, float* __restrict__ out)
{
    double v = 0.0;
    for (int i = threadIdx.x; i < GRID2; i += 256) v += partials[i];
#pragma unroll
    for (int off = 32; off > 0; off >>= 1)
        v += __shfl_down(v, off, 64);
    __shared__ double lsum[4];
    int lane = threadIdx.x & 63;
    int wid  = threadIdx.x >> 6;
    if (lane == 0) lsum[wid] = v;
    __syncthreads();
    if (threadIdx.x == 0)
        out[0] = (float)((lsum[0] + lsum[1] + lsum[2] + lsum[3]) * (1.0 / (double)NTOT));
}

extern "C" void kernel_launch(void* const* d_in, const int* in_sizes, int n_in,
                              void* d_out, int out_size, void* d_ws, size_t ws_size,
                              hipStream_t stream) {
    const float* pred = (const float*)d_in[0];   // [32,4,512,512] f32
    const float* targ = (const float*)d_in[1];   // [32,4,512,512] f32
    // d_in[2] = text_tokens (unused by the loss)
    const float* pos  = (const float*)d_in[3];   // [32,64,2] f32

    double* partials = (double*)d_ws;
    unsigned long long* rowmask =
        (unsigned long long*)((char*)d_ws + ROWMASK_OFF);
    float* out = (float*)d_out;

    // 1) per-row column bitmasks: B*H = 16384 rows
    build_rowmask_kernel<<<(Bb * Hh + 255) / 256, 256, 0, stream>>>(pos, rowmask);

    // 2) main reduction: 2048 blocks x 256 threads, 4 quads/thread, exact cover
    weighted_sq_sum_kernel<<<GRID2, 256, 0, stream>>>(pred, targ, rowmask, partials);

    // 3) finalize
    final_reduce_kernel<<<1, 256, 0, stream>>>(partials, out);
}